// Round 7
// baseline (815.000 us; speedup 1.0000x reference)
//
#include <hip/hip_runtime.h>

#define NN 50000
#define NE 500000
#define HD 128
#define HD2 256
#define NL 4
#define NG 1000

constexpr float MSG_EPS = 1e-7f;
constexpr float LNEPS   = 1e-5f;

typedef float  f32x4  __attribute__((ext_vector_type(4)));
typedef __bf16 bf16x8 __attribute__((ext_vector_type(8)));

__device__ __forceinline__ unsigned short f2b(float f) {
    unsigned int u = __float_as_uint(f);
    unsigned int r = u + 0x7FFFu + ((u >> 16) & 1u);
    return (unsigned short)(r >> 16);
}
__device__ __forceinline__ float b2f(unsigned short h) {
    return __uint_as_float(((unsigned int)h) << 16);
}

// ---------------- node encoder: z0 = bf16(x @ Wn + bn) ----------------
__global__ void k_encode_nodes(const float* __restrict__ x, const float* __restrict__ W,
                               const float* __restrict__ b, unsigned short* __restrict__ zb) {
    int n = blockIdx.x;
    int c = threadIdx.x;  // 128
    float xr[9];
#pragma unroll
    for (int k = 0; k < 9; k++) xr[k] = x[n * 9 + k];
    float acc = b[c];
#pragma unroll
    for (int k = 0; k < 9; k++) acc = fmaf(xr[k], W[k * HD + c], acc);
    zb[n * HD + c] = f2b(acc);
}

// ---------------- weight prep: fp32 -> bf16 transposed ----------------
__global__ void k_prep(const float* __restrict__ W1, const float* __restrict__ W2,
                       unsigned short* __restrict__ W1T, unsigned short* __restrict__ W2T) {
    int idx = blockIdx.x * 256 + threadIdx.x;  // 131072 total
    {
        int k = idx & 127, n = (idx >> 7) & 255, l = idx >> 15;
        W1T[idx] = f2b(W1[(l * 128 + k) * 256 + n]);
    }
    {
        int k = idx & 255, n = (idx >> 8) & 127, l = idx >> 15;
        W2T[idx] = f2b(W2[(l * 256 + k) * 128 + n]);
    }
}

// ---------------- CSR build ----------------
__global__ void k_hist(const int* __restrict__ dst, int* __restrict__ counts) {
    int e = blockIdx.x * blockDim.x + threadIdx.x;
    if (e < NE) atomicAdd(&counts[dst[e]], 1);
}

#define SCAN_B 512
__global__ void k_scan1(const int* __restrict__ counts, int* __restrict__ incl,
                        int* __restrict__ bsum) {
    __shared__ int s[SCAN_B];
    int i = blockIdx.x * SCAN_B + threadIdx.x;
    int v = (i < NN) ? counts[i] : 0;
    s[threadIdx.x] = v;
    __syncthreads();
    for (int off = 1; off < SCAN_B; off <<= 1) {
        int t = (threadIdx.x >= off) ? s[threadIdx.x - off] : 0;
        __syncthreads();
        s[threadIdx.x] += t;
        __syncthreads();
    }
    if (i < NN) incl[i] = s[threadIdx.x];
    if (threadIdx.x == SCAN_B - 1) bsum[blockIdx.x] = s[threadIdx.x];
}

__global__ void k_scan2(const int* __restrict__ bsum, int* __restrict__ boff, int nb) {
    __shared__ int s[128];
    int v = (threadIdx.x < nb) ? bsum[threadIdx.x] : 0;
    s[threadIdx.x] = v;
    __syncthreads();
    for (int off = 1; off < 128; off <<= 1) {
        int t = (threadIdx.x >= off) ? s[threadIdx.x - off] : 0;
        __syncthreads();
        s[threadIdx.x] += t;
        __syncthreads();
    }
    if (threadIdx.x < nb) boff[threadIdx.x] = s[threadIdx.x] - v;  // exclusive
}

__global__ void k_scan3(const int* __restrict__ incl, const int* __restrict__ boff,
                        int* __restrict__ row_start) {
    int i = blockIdx.x * SCAN_B + threadIdx.x;
    if (i < NN) row_start[i + 1] = incl[i] + boff[blockIdx.x];
    if (i == 0) row_start[0] = 0;
}

// pack {attr0, attr1, attr2, src} per CSR slot
__global__ void k_scatter(const int* __restrict__ src, const int* __restrict__ dst,
                          const float* __restrict__ eattr, const int* __restrict__ row_start,
                          int* __restrict__ cursor, float4* __restrict__ aperm) {
    int e = blockIdx.x * blockDim.x + threadIdx.x;
    if (e >= NE) return;
    int d = dst[e];
    int p = row_start[d] + atomicAdd(&cursor[d], 1);
    float4 v;
    v.x = eattr[e * 3 + 0];
    v.y = eattr[e * 3 + 1];
    v.z = eattr[e * 3 + 2];
    v.w = __int_as_float(src[e]);
    aperm[p] = v;
}

// ---------------- per-edge softmax-agg accumulate (2 channels/lane) ----------------
__device__ __forceinline__ void edge_acc(float4 a, unsigned int zz, float2 w0, float2 w1,
                                         float2 w2, float2 bb, float tv, float& num0,
                                         float& num1, float& wm0, float& wm1) {
    float zx = b2f((unsigned short)zz), zy = b2f((unsigned short)(zz >> 16));
    float eax = fmaf(a.x, w0.x, fmaf(a.y, w1.x, fmaf(a.z, w2.x, bb.x)));
    float eay = fmaf(a.x, w0.y, fmaf(a.y, w1.y, fmaf(a.z, w2.y, bb.y)));
    float mx = fmaxf(zx + eax, 0.f) + MSG_EPS;
    float my = fmaxf(zy + eay, 0.f) + MSG_EPS;
    float ex = __expf(tv * mx), ey = __expf(tv * my);
    num0 += ex;
    num1 += ey;
    wm0 = fmaf(mx, ex, wm0);
    wm1 = fmaf(my, ey, wm1);
}

// ---------------- fused layer: aggregate + MLP + next LN, barrier-free ----------------
// Each wave owns 16 nodes end-to-end. Block = 4 independent waves (no __syncthreads).
// zbin/zbout are DISTINCT buffers (ping-pong): gather reads never race next-z writes.
// Per-wave LDS: As 16x136 bf16 (A-tile from agg), Hs 16x268 bf16 (hidden tile).
#define AS_LD 136  // 68 uints, odd stride -> conflict-light
#define HS_LD 268  // 67 uints

__global__ __launch_bounds__(256) void k_layer(
    const unsigned short* __restrict__ zbin, const float4* __restrict__ aperm,
    const int* __restrict__ row_start, const float* __restrict__ We,
    const float* __restrict__ be, const float* __restrict__ t, int layer,
    const unsigned short* __restrict__ W1T, const float* __restrict__ b1l,
    const float* __restrict__ lgl, const float* __restrict__ lbl,
    const unsigned short* __restrict__ W2T, const float* __restrict__ b2l,
    unsigned short* __restrict__ h, const float* __restrict__ gn,
    const float* __restrict__ bn, unsigned short* __restrict__ zbout, int add_residual) {
    __shared__ __align__(16) unsigned short lds[4 * (16 * AS_LD + 16 * HS_LD)];  // 51712 B

    int w = threadIdx.x >> 6, lane = threadIdx.x & 63;
    int base = blockIdx.x * 64 + w * 16;
    if (base >= NN) return;  // no barriers in kernel: early exit is safe
    unsigned short* As = lds + w * (16 * AS_LD + 16 * HS_LD);
    unsigned short* Hs = As + 16 * AS_LD;
    int q = lane >> 4, i = lane & 15;

    // ---------- phase 1: softmax aggregation for 16 nodes; lane owns ch 2l,2l+1 ----
    {
        int c = lane * 2;
        float2 w0 = *(const float2*)&We[c];
        float2 w1 = *(const float2*)&We[HD + c];
        float2 w2 = *(const float2*)&We[2 * HD + c];
        float2 bb = *(const float2*)&be[c];
        float tv = t[layer];
        const unsigned int* z32 = (const unsigned int*)zbin;
        unsigned int* As32 = (unsigned int*)As;
        for (int k = 0; k < 16; k++) {
            int n = base + k;
            int s0 = row_start[n], s1 = row_start[n + 1];
            float num0 = 0.f, num1 = 0.f, wm0 = 0.f, wm1 = 0.f;
            int p = s0;
            for (; p + 4 <= s1; p += 4) {
                float4 a0 = aperm[p], a1 = aperm[p + 1], a2 = aperm[p + 2], a3 = aperm[p + 3];
                unsigned int zz0 = z32[__float_as_int(a0.w) * 64 + lane];
                unsigned int zz1 = z32[__float_as_int(a1.w) * 64 + lane];
                unsigned int zz2 = z32[__float_as_int(a2.w) * 64 + lane];
                unsigned int zz3 = z32[__float_as_int(a3.w) * 64 + lane];
                edge_acc(a0, zz0, w0, w1, w2, bb, tv, num0, num1, wm0, wm1);
                edge_acc(a1, zz1, w0, w1, w2, bb, tv, num0, num1, wm0, wm1);
                edge_acc(a2, zz2, w0, w1, w2, bb, tv, num0, num1, wm0, wm1);
                edge_acc(a3, zz3, w0, w1, w2, bb, tv, num0, num1, wm0, wm1);
            }
            for (; p < s1; p++) {
                float4 a = aperm[p];
                unsigned int zz = z32[__float_as_int(a.w) * 64 + lane];
                edge_acc(a, zz, w0, w1, w2, bb, tv, num0, num1, wm0, wm1);
            }
            unsigned int zn = z32[n * 64 + lane];
            float ox = ((s1 > s0) ? (wm0 / num0) : 0.f) + b2f((unsigned short)zn);
            float oy = ((s1 > s0) ? (wm1 / num1) : 0.f) + b2f((unsigned short)(zn >> 16));
            As32[k * (AS_LD / 2) + lane] = (unsigned int)f2b(ox) | ((unsigned int)f2b(oy) << 16);
        }
    }
    // same-wave ds_write -> ds_read: compiler inserts lgkmcnt wait; no barrier needed

    // ---------- phase 2: GEMM1 16x256 K=128 ----------
    f32x4 acc[16];
#pragma unroll
    for (int ct = 0; ct < 16; ct++) acc[ct] = (f32x4){0.f, 0.f, 0.f, 0.f};
#pragma unroll
    for (int ks = 0; ks < 4; ks++) {
        bf16x8 a = *(const bf16x8*)&As[i * AS_LD + ks * 32 + q * 8];
#pragma unroll
        for (int ct = 0; ct < 16; ct++) {
            bf16x8 bfr = *(const bf16x8*)&W1T[(ct * 16 + i) * HD + ks * 32 + q * 8];
            acc[ct] = __builtin_amdgcn_mfma_f32_16x16x32_bf16(a, bfr, acc[ct], 0, 0, 0);
        }
    }
#pragma unroll
    for (int ct = 0; ct < 16; ct++) {
        float bb = b1l[ct * 16 + i];
#pragma unroll
        for (int r = 0; r < 4; r++) acc[ct][r] += bb;
    }

    // ---------- LN(256)+relu in-register; lane holds rows q*4+r, cols ct*16+i ----
    {
        float s[4] = {0.f, 0.f, 0.f, 0.f}, sq[4] = {0.f, 0.f, 0.f, 0.f};
#pragma unroll
        for (int ct = 0; ct < 16; ct++)
#pragma unroll
            for (int r = 0; r < 4; r++) {
                s[r] += acc[ct][r];
                sq[r] = fmaf(acc[ct][r], acc[ct][r], sq[r]);
            }
#pragma unroll
        for (int m = 8; m >= 1; m >>= 1)
#pragma unroll
            for (int r = 0; r < 4; r++) {
                s[r] += __shfl_xor(s[r], m);
                sq[r] += __shfl_xor(sq[r], m);
            }
        float mu[4], inv[4];
#pragma unroll
        for (int r = 0; r < 4; r++) {
            mu[r] = s[r] * (1.f / 256.f);
            float var = sq[r] * (1.f / 256.f) - mu[r] * mu[r];
            inv[r] = rsqrtf(var + LNEPS);
        }
#pragma unroll
        for (int ct = 0; ct < 16; ct++) {
            float g = lgl[ct * 16 + i];
            float c = lbl[ct * 16 + i];
#pragma unroll
            for (int r = 0; r < 4; r++) {
                float v = fmaxf(fmaf((acc[ct][r] - mu[r]) * inv[r], g, c), 0.f);
                Hs[(q * 4 + r) * HS_LD + ct * 16 + i] = f2b(v);
            }
        }
    }

    // ---------- GEMM2: 16x128, K=256 ----------
    f32x4 acc2[8];
#pragma unroll
    for (int ct = 0; ct < 8; ct++) acc2[ct] = (f32x4){0.f, 0.f, 0.f, 0.f};
#pragma unroll
    for (int ks = 0; ks < 8; ks++) {
        bf16x8 a = *(const bf16x8*)&Hs[i * HS_LD + ks * 32 + q * 8];
#pragma unroll
        for (int ct = 0; ct < 8; ct++) {
            bf16x8 bfr = *(const bf16x8*)&W2T[(ct * 16 + i) * HD2 + ks * 32 + q * 8];
            acc2[ct] = __builtin_amdgcn_mfma_f32_16x16x32_bf16(a, bfr, acc2[ct], 0, 0, 0);
        }
    }

    // ---------- epilogue: hn = acc2 + b2 (+ h_old); store h bf16 ----------
    if (add_residual) {
#pragma unroll
        for (int ct = 0; ct < 8; ct++) {
            float bb = b2l[ct * 16 + i];
#pragma unroll
            for (int r = 0; r < 4; r++) {
                size_t idx = (size_t)(base + q * 4 + r) * HD + ct * 16 + i;
                acc2[ct][r] += bb + b2f(h[idx]);
            }
        }
    } else {
#pragma unroll
        for (int ct = 0; ct < 8; ct++) {
            float bb = b2l[ct * 16 + i];
#pragma unroll
            for (int r = 0; r < 4; r++) acc2[ct][r] += bb;
        }
    }
#pragma unroll
    for (int ct = 0; ct < 8; ct++)
#pragma unroll
        for (int r = 0; r < 4; r++) {
            size_t idx = (size_t)(base + q * 4 + r) * HD + ct * 16 + i;
            h[idx] = f2b(acc2[ct][r]);
        }

    // ---------- LN(128)+relu in-register -> zbout ----------
    {
        float s[4] = {0.f, 0.f, 0.f, 0.f}, sq[4] = {0.f, 0.f, 0.f, 0.f};
#pragma unroll
        for (int ct = 0; ct < 8; ct++)
#pragma unroll
            for (int r = 0; r < 4; r++) {
                s[r] += acc2[ct][r];
                sq[r] = fmaf(acc2[ct][r], acc2[ct][r], sq[r]);
            }
#pragma unroll
        for (int m = 8; m >= 1; m >>= 1)
#pragma unroll
            for (int r = 0; r < 4; r++) {
                s[r] += __shfl_xor(s[r], m);
                sq[r] += __shfl_xor(sq[r], m);
            }
        float mu[4], inv[4];
#pragma unroll
        for (int r = 0; r < 4; r++) {
            mu[r] = s[r] * (1.f / 128.f);
            float var = sq[r] * (1.f / 128.f) - mu[r] * mu[r];
            inv[r] = rsqrtf(var + LNEPS);
        }
#pragma unroll
        for (int ct = 0; ct < 8; ct++) {
            float g = gn[ct * 16 + i];
            float c = bn[ct * 16 + i];
#pragma unroll
            for (int r = 0; r < 4; r++) {
                float v = fmaxf(fmaf((acc2[ct][r] - mu[r]) * inv[r], g, c), 0.f);
                zbout[(size_t)(base + q * 4 + r) * HD + ct * 16 + i] = f2b(v);
            }
        }
    }
}

// ---------------- atomic-free global mean pool (batch is sorted) ----------------
__global__ void k_gbounds(const int* __restrict__ batch, int* __restrict__ gstart) {
    int g = blockIdx.x * blockDim.x + threadIdx.x;
    if (g > NG) return;
    int lo = 0, hi = NN;
    while (lo < hi) {
        int mid = (lo + hi) >> 1;
        if (batch[mid] < g) lo = mid + 1;
        else hi = mid;
    }
    gstart[g] = lo;
}

__global__ void k_pool(const unsigned short* __restrict__ zb, const int* __restrict__ gstart,
                       float* __restrict__ out) {
    int g = blockIdx.x;
    int c = threadIdx.x;  // 128
    int a = gstart[g], b = gstart[g + 1];
    float s0 = 0.f, s1 = 0.f;
    int n = a;
    for (; n + 2 <= b; n += 2) {
        s0 += b2f(zb[(size_t)n * HD + c]);
        s1 += b2f(zb[(size_t)(n + 1) * HD + c]);
    }
    if (n < b) s0 += b2f(zb[(size_t)n * HD + c]);
    out[g * HD + c] = (s0 + s1) / fmaxf((float)(b - a), 1.f);
}

// ---------------- launch ----------------
extern "C" void kernel_launch(void* const* d_in, const int* in_sizes, int n_in, void* d_out,
                              int out_size, void* d_ws, size_t ws_size, hipStream_t stream) {
    const float* x     = (const float*)d_in[0];
    const int* ei      = (const int*)d_in[1];
    const float* eattr = (const float*)d_in[2];
    const int* batch   = (const int*)d_in[3];
    const float* encW  = (const float*)d_in[4];
    const float* encB  = (const float*)d_in[5];
    const float* eW    = (const float*)d_in[6];
    const float* eB    = (const float*)d_in[7];
    const float* ln_g  = (const float*)d_in[8];
    const float* ln_b  = (const float*)d_in[9];
    const float* W1    = (const float*)d_in[10];
    const float* b1    = (const float*)d_in[11];
    const float* mlg   = (const float*)d_in[12];
    const float* mlb   = (const float*)d_in[13];
    const float* W2    = (const float*)d_in[14];
    const float* b2    = (const float*)d_in[15];
    const float* t     = (const float*)d_in[16];
    const int* src = ei;
    const int* dst = ei + NE;

    char* w = (char*)d_ws;
    auto alloc = [&](size_t bytes) {
        char* p = w;
        w += (bytes + 255) & ~size_t(255);
        return p;
    };
    unsigned short* h    = (unsigned short*)alloc(sizeof(unsigned short) * NN * HD);
    unsigned short* zb0  = (unsigned short*)alloc(sizeof(unsigned short) * NN * HD);
    unsigned short* zb1  = (unsigned short*)alloc(sizeof(unsigned short) * NN * HD);
    float4* aperm        = (float4*)alloc(sizeof(float4) * NE);
    int* row_start       = (int*)alloc(sizeof(int) * (NN + 1));
    int* counts          = (int*)alloc(sizeof(int) * NN);
    int* cursor          = (int*)alloc(sizeof(int) * NN);
    int* incl            = (int*)alloc(sizeof(int) * NN);
    int* bsum            = (int*)alloc(sizeof(int) * 128);
    int* boff            = (int*)alloc(sizeof(int) * 128);
    int* gstart          = (int*)alloc(sizeof(int) * (NG + 1));
    unsigned short* W1T  = (unsigned short*)alloc(sizeof(unsigned short) * NL * HD * HD2);
    unsigned short* W2T  = (unsigned short*)alloc(sizeof(unsigned short) * NL * HD2 * HD);

    hipMemsetAsync(counts, 0, sizeof(int) * NN, stream);
    hipMemsetAsync(cursor, 0, sizeof(int) * NN, stream);

    k_prep<<<512, 256, 0, stream>>>(W1, W2, W1T, W2T);
    k_encode_nodes<<<NN, HD, 0, stream>>>(x, encW, encB, zb0);
    k_hist<<<(NE + 255) / 256, 256, 0, stream>>>(dst, counts);
    int nsb = (NN + SCAN_B - 1) / SCAN_B;
    k_scan1<<<nsb, SCAN_B, 0, stream>>>(counts, incl, bsum);
    k_scan2<<<1, 128, 0, stream>>>(bsum, boff, nsb);
    k_scan3<<<nsb, SCAN_B, 0, stream>>>(incl, boff, row_start);
    k_scatter<<<(NE + 255) / 256, 256, 0, stream>>>(src, dst, eattr, row_start, cursor, aperm);
    k_gbounds<<<(NG + 256) / 256, 256, 0, stream>>>(batch, gstart);

    int grid = (NN + 63) / 64;  // 782 blocks x 4 waves; each wave owns 16 nodes
    unsigned short* zbufs[2] = {zb0, zb1};
    for (int l = 0; l < NL; l++) {
        int ln_next = (l + 1) % NL;  // layer 3 fuses the final ln (reuses layer-0 params)
        k_layer<<<grid, 256, 0, stream>>>(
            zbufs[l & 1], aperm, row_start, eW, eB, t, l, W1T + (size_t)l * HD * HD2,
            b1 + l * HD2, mlg + l * HD2, mlb + l * HD2, W2T + (size_t)l * HD2 * HD, b2 + l * HD,
            h, ln_g + ln_next * HD, ln_b + ln_next * HD, zbufs[(l + 1) & 1], l > 0);
    }
    k_pool<<<NG, HD, 0, stream>>>(zbufs[NL & 1], gstart, (float*)d_out);
}

// Round 8
// 596.276 us; speedup vs baseline: 1.3668x; 1.3668x over previous
//
#include <hip/hip_runtime.h>

#define NN 50000
#define NE 500000
#define HD 128
#define HD2 256
#define NL 4
#define NG 1000

constexpr float MSG_EPS = 1e-7f;
constexpr float LNEPS   = 1e-5f;

typedef float  f32x4  __attribute__((ext_vector_type(4)));
typedef __bf16 bf16x8 __attribute__((ext_vector_type(8)));

__device__ __forceinline__ unsigned short f2b(float f) {
    unsigned int u = __float_as_uint(f);
    unsigned int r = u + 0x7FFFu + ((u >> 16) & 1u);
    return (unsigned short)(r >> 16);
}
__device__ __forceinline__ float b2f(unsigned short h) {
    return __uint_as_float(((unsigned int)h) << 16);
}

// ---------------- node encoder: z0 = bf16(x @ Wn + bn) ----------------
__global__ void k_encode_nodes(const float* __restrict__ x, const float* __restrict__ W,
                               const float* __restrict__ b, unsigned short* __restrict__ zb) {
    int n = blockIdx.x;
    int c = threadIdx.x;  // 128
    float xr[9];
#pragma unroll
    for (int k = 0; k < 9; k++) xr[k] = x[n * 9 + k];
    float acc = b[c];
#pragma unroll
    for (int k = 0; k < 9; k++) acc = fmaf(xr[k], W[k * HD + c], acc);
    zb[n * HD + c] = f2b(acc);
}

// ---------------- weight prep: fp32 -> bf16 transposed ----------------
__global__ void k_prep(const float* __restrict__ W1, const float* __restrict__ W2,
                       unsigned short* __restrict__ W1T, unsigned short* __restrict__ W2T) {
    int idx = blockIdx.x * 256 + threadIdx.x;  // 131072 total
    {
        int k = idx & 127, n = (idx >> 7) & 255, l = idx >> 15;
        W1T[idx] = f2b(W1[(l * 128 + k) * 256 + n]);
    }
    {
        int k = idx & 255, n = (idx >> 8) & 127, l = idx >> 15;
        W2T[idx] = f2b(W2[(l * 256 + k) * 128 + n]);
    }
}

// ---------------- CSR build ----------------
__global__ void k_hist(const int* __restrict__ dst, int* __restrict__ counts) {
    int e = blockIdx.x * blockDim.x + threadIdx.x;
    if (e < NE) atomicAdd(&counts[dst[e]], 1);
}

#define SCAN_B 512
__global__ void k_scan1(const int* __restrict__ counts, int* __restrict__ incl,
                        int* __restrict__ bsum) {
    __shared__ int s[SCAN_B];
    int i = blockIdx.x * SCAN_B + threadIdx.x;
    int v = (i < NN) ? counts[i] : 0;
    s[threadIdx.x] = v;
    __syncthreads();
    for (int off = 1; off < SCAN_B; off <<= 1) {
        int t = (threadIdx.x >= off) ? s[threadIdx.x - off] : 0;
        __syncthreads();
        s[threadIdx.x] += t;
        __syncthreads();
    }
    if (i < NN) incl[i] = s[threadIdx.x];
    if (threadIdx.x == SCAN_B - 1) bsum[blockIdx.x] = s[threadIdx.x];
}

__global__ void k_scan2(const int* __restrict__ bsum, int* __restrict__ boff, int nb) {
    __shared__ int s[128];
    int v = (threadIdx.x < nb) ? bsum[threadIdx.x] : 0;
    s[threadIdx.x] = v;
    __syncthreads();
    for (int off = 1; off < 128; off <<= 1) {
        int t = (threadIdx.x >= off) ? s[threadIdx.x - off] : 0;
        __syncthreads();
        s[threadIdx.x] += t;
        __syncthreads();
    }
    if (threadIdx.x < nb) boff[threadIdx.x] = s[threadIdx.x] - v;  // exclusive
}

__global__ void k_scan3(const int* __restrict__ incl, const int* __restrict__ boff,
                        int* __restrict__ row_start) {
    int i = blockIdx.x * SCAN_B + threadIdx.x;
    if (i < NN) row_start[i + 1] = incl[i] + boff[blockIdx.x];
    if (i == 0) row_start[0] = 0;
}

// pack {attr0, attr1, attr2, src} per CSR slot
__global__ void k_scatter(const int* __restrict__ src, const int* __restrict__ dst,
                          const float* __restrict__ eattr, const int* __restrict__ row_start,
                          int* __restrict__ cursor, float4* __restrict__ aperm) {
    int e = blockIdx.x * blockDim.x + threadIdx.x;
    if (e >= NE) return;
    int d = dst[e];
    int p = row_start[d] + atomicAdd(&cursor[d], 1);
    float4 v;
    v.x = eattr[e * 3 + 0];
    v.y = eattr[e * 3 + 1];
    v.z = eattr[e * 3 + 2];
    v.w = __int_as_float(src[e]);
    aperm[p] = v;
}

// ---------------- per-edge softmax-agg accumulate (1 channel/lane) ----------------
__device__ __forceinline__ void edge_acc1(float4 a, float z, float w0, float w1, float w2,
                                          float bb, float tv, float& num, float& wm) {
    float ea = fmaf(a.x, w0, fmaf(a.y, w1, fmaf(a.z, w2, bb)));
    float m = fmaxf(z + ea, 0.f) + MSG_EPS;
    float e = __expf(tv * m);
    num += e;
    wm = fmaf(m, e, wm);
}

// ---------------- softmax aggregation: TWO waves per node, 1 channel/lane ----------
// grid = 25000 blocks x 256 thr: block handles 2 nodes; wave (w>>1) picks node,
// (w&1) picks channel half. 100K waves total for max latency hiding.
__global__ __launch_bounds__(256) void k_aggregate(const unsigned short* __restrict__ zbin,
                                                   const float4* __restrict__ aperm,
                                                   const int* __restrict__ row_start,
                                                   const float* __restrict__ We,
                                                   const float* __restrict__ be,
                                                   const float* __restrict__ t, int layer,
                                                   unsigned short* __restrict__ outb) {
    int w = threadIdx.x >> 6, lane = threadIdx.x & 63;
    int n = blockIdx.x * 2 + (w >> 1);
    if (n >= NN) return;
    int c = ((w & 1) << 6) | lane;
    float w0 = We[c], w1 = We[HD + c], w2 = We[2 * HD + c], bb = be[c];
    float tv = t[layer];
    int s0 = row_start[n], s1 = row_start[n + 1];
    float num = 0.f, wm = 0.f;
    int p = s0;
    for (; p + 4 <= s1; p += 4) {
        float4 a0 = aperm[p], a1 = aperm[p + 1], a2 = aperm[p + 2], a3 = aperm[p + 3];
        float z0 = b2f(zbin[(size_t)__float_as_int(a0.w) * HD + c]);
        float z1 = b2f(zbin[(size_t)__float_as_int(a1.w) * HD + c]);
        float z2 = b2f(zbin[(size_t)__float_as_int(a2.w) * HD + c]);
        float z3 = b2f(zbin[(size_t)__float_as_int(a3.w) * HD + c]);
        edge_acc1(a0, z0, w0, w1, w2, bb, tv, num, wm);
        edge_acc1(a1, z1, w0, w1, w2, bb, tv, num, wm);
        edge_acc1(a2, z2, w0, w1, w2, bb, tv, num, wm);
        edge_acc1(a3, z3, w0, w1, w2, bb, tv, num, wm);
    }
    for (; p < s1; p++) {
        float4 a = aperm[p];
        float z = b2f(zbin[(size_t)__float_as_int(a.w) * HD + c]);
        edge_acc1(a, z, w0, w1, w2, bb, tv, num, wm);
    }
    float zn = b2f(zbin[(size_t)n * HD + c]);
    float o = ((s1 > s0) ? (wm / num) : 0.f) + zn;
    outb[(size_t)n * HD + c] = f2b(o);
}

// ---------------- fused MFMA MLP + next-layer LN+relu ----------------
// hnew = (add? h : 0) + relu(LN(A@W1+b1))@W2+b2 ; h=bf16(hnew); zb=bf16(relu(LN_next(hnew)))
// BM=32, 4 waves. LN stats computed IN-REGISTER from MFMA accumulators; only the
// per-row (sum,sumsq) partials cross waves via 1KB LDS (st1/st2). 3 barriers.
// Register double-buffering (1-step lookahead) on A/B fragments in both GEMMs.
#define BM 32
#define HS_LD 264  // bf16 row stride (256+8)

__global__ __launch_bounds__(256) void k_mlp(const unsigned short* __restrict__ outb,
                                             const unsigned short* __restrict__ W1T,
                                             const float* __restrict__ b1l,
                                             const float* __restrict__ lgl,
                                             const float* __restrict__ lbl,
                                             const unsigned short* __restrict__ W2T,
                                             const float* __restrict__ b2l,
                                             unsigned short* __restrict__ h,
                                             const float* __restrict__ gn,
                                             const float* __restrict__ bn,
                                             unsigned short* __restrict__ zb,
                                             int add_residual) {
    __shared__ __align__(16) unsigned short Hs[BM * HS_LD];  // 16896 B
    __shared__ __align__(16) float2 st1[2][16][4];           // 1024 B: [rt][row4][wave]
    __shared__ __align__(16) float2 st2[2][16][4];           // 1024 B

    int nb = blockIdx.x * BM;
    int tid = threadIdx.x;
    int w = tid >> 6, lane = tid & 63, q = lane >> 4, i = lane & 15;

    // ---- GEMM1: 32x256, K=128; A from global bf16 outb, 1-step lookahead ----
    f32x4 acc[2][4];
#pragma unroll
    for (int rt = 0; rt < 2; rt++)
#pragma unroll
        for (int ct = 0; ct < 4; ct++) acc[rt][ct] = (f32x4){0.f, 0.f, 0.f, 0.f};

    bf16x8 acur[2], bcur[4];
#pragma unroll
    for (int rt = 0; rt < 2; rt++) {
        int row = nb + rt * 16 + i;
        acur[rt] = (row < NN) ? *(const bf16x8*)&outb[(size_t)row * HD + q * 8]
                              : (bf16x8)(__bf16)0.f;
    }
#pragma unroll
    for (int ct = 0; ct < 4; ct++)
        bcur[ct] = *(const bf16x8*)&W1T[(w * 64 + ct * 16 + i) * HD + q * 8];

#pragma unroll
    for (int ks = 0; ks < 4; ks++) {
        bf16x8 anxt[2], bnxt[4];
        if (ks < 3) {
#pragma unroll
            for (int rt = 0; rt < 2; rt++) {
                int row = nb + rt * 16 + i;
                anxt[rt] = (row < NN)
                               ? *(const bf16x8*)&outb[(size_t)row * HD + (ks + 1) * 32 + q * 8]
                               : (bf16x8)(__bf16)0.f;
            }
#pragma unroll
            for (int ct = 0; ct < 4; ct++)
                bnxt[ct] =
                    *(const bf16x8*)&W1T[(w * 64 + ct * 16 + i) * HD + (ks + 1) * 32 + q * 8];
        }
#pragma unroll
        for (int rt = 0; rt < 2; rt++)
#pragma unroll
            for (int ct = 0; ct < 4; ct++)
                acc[rt][ct] =
                    __builtin_amdgcn_mfma_f32_16x16x32_bf16(acur[rt], bcur[ct], acc[rt][ct],
                                                            0, 0, 0);
        if (ks < 3) {
#pragma unroll
            for (int rt = 0; rt < 2; rt++) acur[rt] = anxt[rt];
#pragma unroll
            for (int ct = 0; ct < 4; ct++) bcur[ct] = bnxt[ct];
        }
    }

    // ---- +b1 ----
#pragma unroll
    for (int ct = 0; ct < 4; ct++) {
        float bb = b1l[w * 64 + ct * 16 + i];
#pragma unroll
        for (int rt = 0; rt < 2; rt++)
#pragma unroll
            for (int r = 0; r < 4; r++) acc[rt][ct][r] += bb;
    }

    // ---- LN(256) stats in-register + cross-wave exchange ----
    {
        float sv[2][4], qv[2][4];
#pragma unroll
        for (int rt = 0; rt < 2; rt++)
#pragma unroll
            for (int r = 0; r < 4; r++) {
                float s = acc[rt][0][r] + acc[rt][1][r] + acc[rt][2][r] + acc[rt][3][r];
                float sq = 0.f;
#pragma unroll
                for (int ct = 0; ct < 4; ct++) sq = fmaf(acc[rt][ct][r], acc[rt][ct][r], sq);
                sv[rt][r] = s;
                qv[rt][r] = sq;
            }
#pragma unroll
        for (int m = 1; m <= 8; m <<= 1)
#pragma unroll
            for (int rt = 0; rt < 2; rt++)
#pragma unroll
                for (int r = 0; r < 4; r++) {
                    sv[rt][r] += __shfl_xor(sv[rt][r], m);
                    qv[rt][r] += __shfl_xor(qv[rt][r], m);
                }
        if (i == 0) {
#pragma unroll
            for (int rt = 0; rt < 2; rt++)
#pragma unroll
                for (int r = 0; r < 4; r++)
                    st1[rt][q * 4 + r][w] = make_float2(sv[rt][r], qv[rt][r]);
        }
    }
    __syncthreads();

    {
        float mu[2][4], inv[2][4];
#pragma unroll
        for (int rt = 0; rt < 2; rt++)
#pragma unroll
            for (int r = 0; r < 4; r++) {
                const float4* sp = (const float4*)&st1[rt][q * 4 + r][0];
                float4 a = sp[0], b = sp[1];
                float S = a.x + a.z + b.x + b.z;
                float Q = a.y + a.w + b.y + b.w;
                float m_ = S * (1.f / 256.f);
                float v_ = Q * (1.f / 256.f) - m_ * m_;
                mu[rt][r] = m_;
                inv[rt][r] = rsqrtf(v_ + LNEPS);
            }
        // apply LN+relu in-register, pack bf16 -> Hs (C-layout scatter)
#pragma unroll
        for (int ct = 0; ct < 4; ct++) {
            float g = lgl[w * 64 + ct * 16 + i];
            float c = lbl[w * 64 + ct * 16 + i];
#pragma unroll
            for (int rt = 0; rt < 2; rt++)
#pragma unroll
                for (int r = 0; r < 4; r++) {
                    float v =
                        fmaxf(fmaf((acc[rt][ct][r] - mu[rt][r]) * inv[rt][r], g, c), 0.f);
                    Hs[(rt * 16 + q * 4 + r) * HS_LD + w * 64 + ct * 16 + i] = f2b(v);
                }
        }
    }
    __syncthreads();

    // ---- residual prefetch (independent of GEMM2) ----
    unsigned short hold[2][2][4] = {};
    if (add_residual) {
#pragma unroll
        for (int rt = 0; rt < 2; rt++)
#pragma unroll
            for (int ct = 0; ct < 2; ct++)
#pragma unroll
                for (int r = 0; r < 4; r++) {
                    int row = nb + rt * 16 + q * 4 + r;
                    hold[rt][ct][r] =
                        (row < NN) ? h[(size_t)row * HD + w * 32 + ct * 16 + i] : 0;
                }
    }

    // ---- GEMM2: 32x128, K=256; A from Hs, 1-step lookahead ----
    f32x4 acc2[2][2];
#pragma unroll
    for (int rt = 0; rt < 2; rt++)
#pragma unroll
        for (int ct = 0; ct < 2; ct++) acc2[rt][ct] = (f32x4){0.f, 0.f, 0.f, 0.f};

    bf16x8 hc[2], bc[2];
#pragma unroll
    for (int rt = 0; rt < 2; rt++) hc[rt] = *(const bf16x8*)&Hs[(rt * 16 + i) * HS_LD + q * 8];
#pragma unroll
    for (int ct = 0; ct < 2; ct++)
        bc[ct] = *(const bf16x8*)&W2T[(w * 32 + ct * 16 + i) * HD2 + q * 8];

#pragma unroll
    for (int ks = 0; ks < 8; ks++) {
        bf16x8 hn[2], bn2[2];
        if (ks < 7) {
#pragma unroll
            for (int rt = 0; rt < 2; rt++)
                hn[rt] = *(const bf16x8*)&Hs[(rt * 16 + i) * HS_LD + (ks + 1) * 32 + q * 8];
#pragma unroll
            for (int ct = 0; ct < 2; ct++)
                bn2[ct] =
                    *(const bf16x8*)&W2T[(w * 32 + ct * 16 + i) * HD2 + (ks + 1) * 32 + q * 8];
        }
#pragma unroll
        for (int rt = 0; rt < 2; rt++)
#pragma unroll
            for (int ct = 0; ct < 2; ct++)
                acc2[rt][ct] = __builtin_amdgcn_mfma_f32_16x16x32_bf16(hc[rt], bc[ct],
                                                                      acc2[rt][ct], 0, 0, 0);
        if (ks < 7) {
#pragma unroll
            for (int rt = 0; rt < 2; rt++) hc[rt] = hn[rt];
#pragma unroll
            for (int ct = 0; ct < 2; ct++) bc[ct] = bn2[ct];
        }
    }

    // ---- epilogue: hn = acc2 + b2 (+ h_old); store h bf16 ----
#pragma unroll
    for (int ct = 0; ct < 2; ct++) {
        float bb = b2l[w * 32 + ct * 16 + i];
#pragma unroll
        for (int rt = 0; rt < 2; rt++)
#pragma unroll
            for (int r = 0; r < 4; r++) {
                float v = acc2[rt][ct][r] + bb;
                if (add_residual) v += b2f(hold[rt][ct][r]);
                acc2[rt][ct][r] = v;
                int row = nb + rt * 16 + q * 4 + r;
                if (row < NN) h[(size_t)row * HD + w * 32 + ct * 16 + i] = f2b(v);
            }
    }

    // ---- LN(128) stats in-register + cross-wave exchange ----
    {
        float sv[2][4], qv[2][4];
#pragma unroll
        for (int rt = 0; rt < 2; rt++)
#pragma unroll
            for (int r = 0; r < 4; r++) {
                sv[rt][r] = acc2[rt][0][r] + acc2[rt][1][r];
                qv[rt][r] = fmaf(acc2[rt][0][r], acc2[rt][0][r],
                                 acc2[rt][1][r] * acc2[rt][1][r]);
            }
#pragma unroll
        for (int m = 1; m <= 8; m <<= 1)
#pragma unroll
            for (int rt = 0; rt < 2; rt++)
#pragma unroll
                for (int r = 0; r < 4; r++) {
                    sv[rt][r] += __shfl_xor(sv[rt][r], m);
                    qv[rt][r] += __shfl_xor(qv[rt][r], m);
                }
        if (i == 0) {
#pragma unroll
            for (int rt = 0; rt < 2; rt++)
#pragma unroll
                for (int r = 0; r < 4; r++)
                    st2[rt][q * 4 + r][w] = make_float2(sv[rt][r], qv[rt][r]);
        }
    }
    __syncthreads();

    {
#pragma unroll
        for (int rt = 0; rt < 2; rt++)
#pragma unroll
            for (int r = 0; r < 4; r++) {
                const float4* sp = (const float4*)&st2[rt][q * 4 + r][0];
                float4 a = sp[0], b = sp[1];
                float S = a.x + a.z + b.x + b.z;
                float Q = a.y + a.w + b.y + b.w;
                float m_ = S * (1.f / 128.f);
                float v_ = Q * (1.f / 128.f) - m_ * m_;
                float iv = rsqrtf(v_ + LNEPS);
#pragma unroll
                for (int ct = 0; ct < 2; ct++) {
                    float g = gn[w * 32 + ct * 16 + i];
                    float c = bn[w * 32 + ct * 16 + i];
                    float v = fmaxf(fmaf((acc2[rt][ct][r] - m_) * iv, g, c), 0.f);
                    int row = nb + rt * 16 + q * 4 + r;
                    if (row < NN) zb[(size_t)row * HD + w * 32 + ct * 16 + i] = f2b(v);
                }
            }
    }
}

// ---------------- atomic-free global mean pool (batch is sorted) ----------------
__global__ void k_gbounds(const int* __restrict__ batch, int* __restrict__ gstart) {
    int g = blockIdx.x * blockDim.x + threadIdx.x;
    if (g > NG) return;
    int lo = 0, hi = NN;
    while (lo < hi) {
        int mid = (lo + hi) >> 1;
        if (batch[mid] < g) lo = mid + 1;
        else hi = mid;
    }
    gstart[g] = lo;
}

__global__ void k_pool(const unsigned short* __restrict__ zb, const int* __restrict__ gstart,
                       float* __restrict__ out) {
    int g = blockIdx.x;
    int c = threadIdx.x;  // 128
    int a = gstart[g], b = gstart[g + 1];
    float s0 = 0.f, s1 = 0.f;
    int n = a;
    for (; n + 2 <= b; n += 2) {
        s0 += b2f(zb[(size_t)n * HD + c]);
        s1 += b2f(zb[(size_t)(n + 1) * HD + c]);
    }
    if (n < b) s0 += b2f(zb[(size_t)n * HD + c]);
    out[g * HD + c] = (s0 + s1) / fmaxf((float)(b - a), 1.f);
}

// ---------------- launch ----------------
extern "C" void kernel_launch(void* const* d_in, const int* in_sizes, int n_in, void* d_out,
                              int out_size, void* d_ws, size_t ws_size, hipStream_t stream) {
    const float* x     = (const float*)d_in[0];
    const int* ei      = (const int*)d_in[1];
    const float* eattr = (const float*)d_in[2];
    const int* batch   = (const int*)d_in[3];
    const float* encW  = (const float*)d_in[4];
    const float* encB  = (const float*)d_in[5];
    const float* eW    = (const float*)d_in[6];
    const float* eB    = (const float*)d_in[7];
    const float* ln_g  = (const float*)d_in[8];
    const float* ln_b  = (const float*)d_in[9];
    const float* W1    = (const float*)d_in[10];
    const float* b1    = (const float*)d_in[11];
    const float* mlg   = (const float*)d_in[12];
    const float* mlb   = (const float*)d_in[13];
    const float* W2    = (const float*)d_in[14];
    const float* b2    = (const float*)d_in[15];
    const float* t     = (const float*)d_in[16];
    const int* src = ei;
    const int* dst = ei + NE;

    char* w = (char*)d_ws;
    auto alloc = [&](size_t bytes) {
        char* p = w;
        w += (bytes + 255) & ~size_t(255);
        return p;
    };
    unsigned short* h    = (unsigned short*)alloc(sizeof(unsigned short) * NN * HD);
    unsigned short* zb   = (unsigned short*)alloc(sizeof(unsigned short) * NN * HD);
    unsigned short* outb = (unsigned short*)alloc(sizeof(unsigned short) * NN * HD);
    float4* aperm        = (float4*)alloc(sizeof(float4) * NE);
    int* row_start       = (int*)alloc(sizeof(int) * (NN + 1));
    int* counts          = (int*)alloc(sizeof(int) * NN);
    int* cursor          = (int*)alloc(sizeof(int) * NN);
    int* incl            = (int*)alloc(sizeof(int) * NN);
    int* bsum            = (int*)alloc(sizeof(int) * 128);
    int* boff            = (int*)alloc(sizeof(int) * 128);
    int* gstart          = (int*)alloc(sizeof(int) * (NG + 1));
    unsigned short* W1T  = (unsigned short*)alloc(sizeof(unsigned short) * NL * HD * HD2);
    unsigned short* W2T  = (unsigned short*)alloc(sizeof(unsigned short) * NL * HD2 * HD);

    hipMemsetAsync(counts, 0, sizeof(int) * NN, stream);
    hipMemsetAsync(cursor, 0, sizeof(int) * NN, stream);

    k_prep<<<512, 256, 0, stream>>>(W1, W2, W1T, W2T);
    k_encode_nodes<<<NN, HD, 0, stream>>>(x, encW, encB, zb);
    k_hist<<<(NE + 255) / 256, 256, 0, stream>>>(dst, counts);
    int nsb = (NN + SCAN_B - 1) / SCAN_B;
    k_scan1<<<nsb, SCAN_B, 0, stream>>>(counts, incl, bsum);
    k_scan2<<<1, 128, 0, stream>>>(bsum, boff, nsb);
    k_scan3<<<nsb, SCAN_B, 0, stream>>>(incl, boff, row_start);
    k_scatter<<<(NE + 255) / 256, 256, 0, stream>>>(src, dst, eattr, row_start, cursor, aperm);
    k_gbounds<<<(NG + 256) / 256, 256, 0, stream>>>(batch, gstart);

    for (int l = 0; l < NL; l++) {
        k_aggregate<<<(NN + 1) / 2, 256, 0, stream>>>(zb, aperm, row_start, eW, eB, t, l, outb);
        int ln_next = (l + 1) % NL;  // layer 3 fuses the final ln (reuses layer-0 params)
        k_mlp<<<(NN + BM - 1) / BM, 256, 0, stream>>>(
            outb, W1T + (size_t)l * HD * HD2, b1 + l * HD2, mlg + l * HD2, mlb + l * HD2,
            W2T + (size_t)l * HD2 * HD, b2 + l * HD, h, ln_g + ln_next * HD,
            ln_b + ln_next * HD, zb, l > 0);
    }
    k_pool<<<NG, HD, 0, stream>>>(zb, gstart, (float*)d_out);
}

// Round 9
// 506.105 us; speedup vs baseline: 1.6103x; 1.1782x over previous
//
#include <hip/hip_runtime.h>

#define NN 50000
#define NE 500000
#define HD 128
#define HD2 256
#define NL 4
#define NG 1000

constexpr float MSG_EPS = 1e-7f;
constexpr float LNEPS   = 1e-5f;

typedef float  f32x4  __attribute__((ext_vector_type(4)));
typedef __bf16 bf16x8 __attribute__((ext_vector_type(8)));

__device__ __forceinline__ unsigned short f2b(float f) {
    unsigned int u = __float_as_uint(f);
    unsigned int r = u + 0x7FFFu + ((u >> 16) & 1u);
    return (unsigned short)(r >> 16);
}
__device__ __forceinline__ float b2f(unsigned short h) {
    return __uint_as_float(((unsigned int)h) << 16);
}
__device__ __forceinline__ unsigned int pack2(float a, float b) {
    return (unsigned int)f2b(a) | ((unsigned int)f2b(b) << 16);
}

// ---------------- node encoder: z0 = bf16(x @ Wn + bn) ----------------
__global__ void k_encode_nodes(const float* __restrict__ x, const float* __restrict__ W,
                               const float* __restrict__ b, unsigned short* __restrict__ zb) {
    int n = blockIdx.x;
    int c = threadIdx.x;  // 128
    float xr[9];
#pragma unroll
    for (int k = 0; k < 9; k++) xr[k] = x[n * 9 + k];
    float acc = b[c];
#pragma unroll
    for (int k = 0; k < 9; k++) acc = fmaf(xr[k], W[k * HD + c], acc);
    zb[n * HD + c] = f2b(acc);
}

// ---------------- weight prep: fp32 -> bf16 transposed ----------------
__global__ void k_prep(const float* __restrict__ W1, const float* __restrict__ W2,
                       unsigned short* __restrict__ W1T, unsigned short* __restrict__ W2T) {
    int idx = blockIdx.x * 256 + threadIdx.x;  // 131072 total
    {
        int k = idx & 127, n = (idx >> 7) & 255, l = idx >> 15;
        W1T[idx] = f2b(W1[(l * 128 + k) * 256 + n]);
    }
    {
        int k = idx & 255, n = (idx >> 8) & 127, l = idx >> 15;
        W2T[idx] = f2b(W2[(l * 256 + k) * 128 + n]);
    }
}

// ---------------- CSR build ----------------
__global__ void k_hist(const int* __restrict__ dst, int* __restrict__ counts) {
    int e = blockIdx.x * blockDim.x + threadIdx.x;
    if (e < NE) atomicAdd(&counts[dst[e]], 1);
}

#define SCAN_B 512
__global__ void k_scan1(const int* __restrict__ counts, int* __restrict__ incl,
                        int* __restrict__ bsum) {
    __shared__ int s[SCAN_B];
    int i = blockIdx.x * SCAN_B + threadIdx.x;
    int v = (i < NN) ? counts[i] : 0;
    s[threadIdx.x] = v;
    __syncthreads();
    for (int off = 1; off < SCAN_B; off <<= 1) {
        int t = (threadIdx.x >= off) ? s[threadIdx.x - off] : 0;
        __syncthreads();
        s[threadIdx.x] += t;
        __syncthreads();
    }
    if (i < NN) incl[i] = s[threadIdx.x];
    if (threadIdx.x == SCAN_B - 1) bsum[blockIdx.x] = s[threadIdx.x];
}

__global__ void k_scan2(const int* __restrict__ bsum, int* __restrict__ boff, int nb) {
    __shared__ int s[128];
    int v = (threadIdx.x < nb) ? bsum[threadIdx.x] : 0;
    s[threadIdx.x] = v;
    __syncthreads();
    for (int off = 1; off < 128; off <<= 1) {
        int t = (threadIdx.x >= off) ? s[threadIdx.x - off] : 0;
        __syncthreads();
        s[threadIdx.x] += t;
        __syncthreads();
    }
    if (threadIdx.x < nb) boff[threadIdx.x] = s[threadIdx.x] - v;  // exclusive
}

__global__ void k_scan3(const int* __restrict__ incl, const int* __restrict__ boff,
                        int* __restrict__ row_start) {
    int i = blockIdx.x * SCAN_B + threadIdx.x;
    if (i < NN) row_start[i + 1] = incl[i] + boff[blockIdx.x];
    if (i == 0) row_start[0] = 0;
}

// pack {attr0, attr1, attr2, src} per CSR slot
__global__ void k_scatter(const int* __restrict__ src, const int* __restrict__ dst,
                          const float* __restrict__ eattr, const int* __restrict__ row_start,
                          int* __restrict__ cursor, float4* __restrict__ aperm) {
    int e = blockIdx.x * blockDim.x + threadIdx.x;
    if (e >= NE) return;
    int d = dst[e];
    int p = row_start[d] + atomicAdd(&cursor[d], 1);
    float4 v;
    v.x = eattr[e * 3 + 0];
    v.y = eattr[e * 3 + 1];
    v.z = eattr[e * 3 + 2];
    v.w = __int_as_float(src[e]);
    aperm[p] = v;
}

// ---------------- per-edge softmax-agg accumulate (2 channels/lane) ----------------
__device__ __forceinline__ void edge_acc2(float4 a, unsigned int zz, float2 w0, float2 w1,
                                          float2 w2, float2 bb, float tv, float& num0,
                                          float& num1, float& wm0, float& wm1) {
    float zx = b2f((unsigned short)zz), zy = b2f((unsigned short)(zz >> 16));
    float eax = fmaf(a.x, w0.x, fmaf(a.y, w1.x, fmaf(a.z, w2.x, bb.x)));
    float eay = fmaf(a.x, w0.y, fmaf(a.y, w1.y, fmaf(a.z, w2.y, bb.y)));
    float mx = fmaxf(zx + eax, 0.f) + MSG_EPS;
    float my = fmaxf(zy + eay, 0.f) + MSG_EPS;
    float ex = __expf(tv * mx), ey = __expf(tv * my);
    num0 += ex;
    num1 += ey;
    wm0 = fmaf(mx, ex, wm0);
    wm1 = fmaf(my, ey, wm1);
}

// ---------------- softmax aggregation: one wave per node, 2 channels/lane ----------
__global__ __launch_bounds__(256) void k_aggregate(const unsigned short* __restrict__ zbin,
                                                   const float4* __restrict__ aperm,
                                                   const int* __restrict__ row_start,
                                                   const float* __restrict__ We,
                                                   const float* __restrict__ be,
                                                   const float* __restrict__ t, int layer,
                                                   unsigned int* __restrict__ outb) {
    int w = threadIdx.x >> 6, lane = threadIdx.x & 63;
    int n = blockIdx.x * 4 + w;
    if (n >= NN) return;
    int c = lane * 2;
    float2 w0 = *(const float2*)&We[c];
    float2 w1 = *(const float2*)&We[HD + c];
    float2 w2 = *(const float2*)&We[2 * HD + c];
    float2 bb = *(const float2*)&be[c];
    float tv = t[layer];
    int s0 = row_start[n], s1 = row_start[n + 1];
    float num0 = 0.f, num1 = 0.f, wm0 = 0.f, wm1 = 0.f;
    const unsigned int* z32 = (const unsigned int*)zbin;
    int p = s0;
    for (; p + 4 <= s1; p += 4) {
        float4 a0 = aperm[p], a1 = aperm[p + 1], a2 = aperm[p + 2], a3 = aperm[p + 3];
        unsigned int zz0 = z32[(size_t)__float_as_int(a0.w) * 64 + lane];
        unsigned int zz1 = z32[(size_t)__float_as_int(a1.w) * 64 + lane];
        unsigned int zz2 = z32[(size_t)__float_as_int(a2.w) * 64 + lane];
        unsigned int zz3 = z32[(size_t)__float_as_int(a3.w) * 64 + lane];
        edge_acc2(a0, zz0, w0, w1, w2, bb, tv, num0, num1, wm0, wm1);
        edge_acc2(a1, zz1, w0, w1, w2, bb, tv, num0, num1, wm0, wm1);
        edge_acc2(a2, zz2, w0, w1, w2, bb, tv, num0, num1, wm0, wm1);
        edge_acc2(a3, zz3, w0, w1, w2, bb, tv, num0, num1, wm0, wm1);
    }
    for (; p < s1; p++) {
        float4 a = aperm[p];
        unsigned int zz = z32[(size_t)__float_as_int(a.w) * 64 + lane];
        edge_acc2(a, zz, w0, w1, w2, bb, tv, num0, num1, wm0, wm1);
    }
    unsigned int zn = z32[(size_t)n * 64 + lane];
    float ox = ((s1 > s0) ? (wm0 / num0) : 0.f) + b2f((unsigned short)zn);
    float oy = ((s1 > s0) ? (wm1 / num1) : 0.f) + b2f((unsigned short)(zn >> 16));
    outb[(size_t)n * 64 + lane] = pack2(ox, oy);
}

// ---------------- fused MFMA MLP + next-layer LN+relu ----------------
// hnew = (add? h : 0) + relu(LN(A@W1+b1))@W2+b2 ; h=bf16(hnew); zb=bf16(relu(LN_next(hnew)))
// BM=32, 4 waves. In-register LN1 stats (st1 LDS exchange). Register lookahead GEMMs.
// NEW: GEMM2 out -> bf16 LDS tile Ht (C-layout scatter), then row-wise COALESCED epilogue
// (uint loads/stores for h residual, h store, zb store) + in-wave LN(128).
#define BM 32
#define HS_LD 264  // bf16 row stride (256+8)
#define HT_LD 136  // bf16 row stride (128+8); as uint: 68

__global__ __launch_bounds__(256) void k_mlp(const unsigned short* __restrict__ outb,
                                             const unsigned short* __restrict__ W1T,
                                             const float* __restrict__ b1l,
                                             const float* __restrict__ lgl,
                                             const float* __restrict__ lbl,
                                             const unsigned short* __restrict__ W2T,
                                             const float* __restrict__ b2l,
                                             unsigned short* __restrict__ h,
                                             const float* __restrict__ gn,
                                             const float* __restrict__ bn,
                                             unsigned short* __restrict__ zb,
                                             int add_residual) {
    __shared__ __align__(16) unsigned short Hs[BM * HS_LD];  // 16896 B
    __shared__ __align__(16) unsigned short Ht[BM * HT_LD];  // 8704 B
    __shared__ __align__(16) float2 st1[2][16][4];           // 1024 B

    int nb = blockIdx.x * BM;
    int tid = threadIdx.x;
    int w = tid >> 6, lane = tid & 63, q = lane >> 4, i = lane & 15;

    // ---- GEMM1: 32x256, K=128; A from global bf16 outb, 1-step lookahead ----
    f32x4 acc[2][4];
#pragma unroll
    for (int rt = 0; rt < 2; rt++)
#pragma unroll
        for (int ct = 0; ct < 4; ct++) acc[rt][ct] = (f32x4){0.f, 0.f, 0.f, 0.f};

    bf16x8 acur[2], bcur[4];
#pragma unroll
    for (int rt = 0; rt < 2; rt++) {
        int row = nb + rt * 16 + i;
        acur[rt] = (row < NN) ? *(const bf16x8*)&outb[(size_t)row * HD + q * 8]
                              : (bf16x8)(__bf16)0.f;
    }
#pragma unroll
    for (int ct = 0; ct < 4; ct++)
        bcur[ct] = *(const bf16x8*)&W1T[(w * 64 + ct * 16 + i) * HD + q * 8];

#pragma unroll
    for (int ks = 0; ks < 4; ks++) {
        bf16x8 anxt[2], bnxt[4];
        if (ks < 3) {
#pragma unroll
            for (int rt = 0; rt < 2; rt++) {
                int row = nb + rt * 16 + i;
                anxt[rt] = (row < NN)
                               ? *(const bf16x8*)&outb[(size_t)row * HD + (ks + 1) * 32 + q * 8]
                               : (bf16x8)(__bf16)0.f;
            }
#pragma unroll
            for (int ct = 0; ct < 4; ct++)
                bnxt[ct] =
                    *(const bf16x8*)&W1T[(w * 64 + ct * 16 + i) * HD + (ks + 1) * 32 + q * 8];
        }
#pragma unroll
        for (int rt = 0; rt < 2; rt++)
#pragma unroll
            for (int ct = 0; ct < 4; ct++)
                acc[rt][ct] =
                    __builtin_amdgcn_mfma_f32_16x16x32_bf16(acur[rt], bcur[ct], acc[rt][ct],
                                                            0, 0, 0);
        if (ks < 3) {
#pragma unroll
            for (int rt = 0; rt < 2; rt++) acur[rt] = anxt[rt];
#pragma unroll
            for (int ct = 0; ct < 4; ct++) bcur[ct] = bnxt[ct];
        }
    }

    // ---- +b1 ----
#pragma unroll
    for (int ct = 0; ct < 4; ct++) {
        float bb = b1l[w * 64 + ct * 16 + i];
#pragma unroll
        for (int rt = 0; rt < 2; rt++)
#pragma unroll
            for (int r = 0; r < 4; r++) acc[rt][ct][r] += bb;
    }

    // ---- LN(256) stats in-register + cross-wave exchange ----
    {
        float sv[2][4], qv[2][4];
#pragma unroll
        for (int rt = 0; rt < 2; rt++)
#pragma unroll
            for (int r = 0; r < 4; r++) {
                float s = acc[rt][0][r] + acc[rt][1][r] + acc[rt][2][r] + acc[rt][3][r];
                float sq = 0.f;
#pragma unroll
                for (int ct = 0; ct < 4; ct++) sq = fmaf(acc[rt][ct][r], acc[rt][ct][r], sq);
                sv[rt][r] = s;
                qv[rt][r] = sq;
            }
#pragma unroll
        for (int m = 1; m <= 8; m <<= 1)
#pragma unroll
            for (int rt = 0; rt < 2; rt++)
#pragma unroll
                for (int r = 0; r < 4; r++) {
                    sv[rt][r] += __shfl_xor(sv[rt][r], m);
                    qv[rt][r] += __shfl_xor(qv[rt][r], m);
                }
        if (i == 0) {
#pragma unroll
            for (int rt = 0; rt < 2; rt++)
#pragma unroll
                for (int r = 0; r < 4; r++)
                    st1[rt][q * 4 + r][w] = make_float2(sv[rt][r], qv[rt][r]);
        }
    }
    __syncthreads();

    {
        float mu[2][4], inv[2][4];
#pragma unroll
        for (int rt = 0; rt < 2; rt++)
#pragma unroll
            for (int r = 0; r < 4; r++) {
                const float4* sp = (const float4*)&st1[rt][q * 4 + r][0];
                float4 a = sp[0], b = sp[1];
                float S = a.x + a.z + b.x + b.z;
                float Q = a.y + a.w + b.y + b.w;
                float m_ = S * (1.f / 256.f);
                float v_ = Q * (1.f / 256.f) - m_ * m_;
                mu[rt][r] = m_;
                inv[rt][r] = rsqrtf(v_ + LNEPS);
            }
#pragma unroll
        for (int ct = 0; ct < 4; ct++) {
            float g = lgl[w * 64 + ct * 16 + i];
            float c = lbl[w * 64 + ct * 16 + i];
#pragma unroll
            for (int rt = 0; rt < 2; rt++)
#pragma unroll
                for (int r = 0; r < 4; r++) {
                    float v =
                        fmaxf(fmaf((acc[rt][ct][r] - mu[rt][r]) * inv[rt][r], g, c), 0.f);
                    Hs[(rt * 16 + q * 4 + r) * HS_LD + w * 64 + ct * 16 + i] = f2b(v);
                }
        }
    }
    __syncthreads();

    // ---- GEMM2: 32x128, K=256; A from Hs, 1-step lookahead ----
    f32x4 acc2[2][2];
#pragma unroll
    for (int rt = 0; rt < 2; rt++)
#pragma unroll
        for (int ct = 0; ct < 2; ct++) acc2[rt][ct] = (f32x4){0.f, 0.f, 0.f, 0.f};

    bf16x8 hc[2], bc[2];
#pragma unroll
    for (int rt = 0; rt < 2; rt++) hc[rt] = *(const bf16x8*)&Hs[(rt * 16 + i) * HS_LD + q * 8];
#pragma unroll
    for (int ct = 0; ct < 2; ct++)
        bc[ct] = *(const bf16x8*)&W2T[(w * 32 + ct * 16 + i) * HD2 + q * 8];

#pragma unroll
    for (int ks = 0; ks < 8; ks++) {
        bf16x8 hn[2], bn2[2];
        if (ks < 7) {
#pragma unroll
            for (int rt = 0; rt < 2; rt++)
                hn[rt] = *(const bf16x8*)&Hs[(rt * 16 + i) * HS_LD + (ks + 1) * 32 + q * 8];
#pragma unroll
            for (int ct = 0; ct < 2; ct++)
                bn2[ct] =
                    *(const bf16x8*)&W2T[(w * 32 + ct * 16 + i) * HD2 + (ks + 1) * 32 + q * 8];
        }
#pragma unroll
        for (int rt = 0; rt < 2; rt++)
#pragma unroll
            for (int ct = 0; ct < 2; ct++)
                acc2[rt][ct] = __builtin_amdgcn_mfma_f32_16x16x32_bf16(hc[rt], bc[ct],
                                                                      acc2[rt][ct], 0, 0, 0);
        if (ks < 7) {
#pragma unroll
            for (int rt = 0; rt < 2; rt++) hc[rt] = hn[rt];
#pragma unroll
            for (int ct = 0; ct < 2; ct++) bc[ct] = bn2[ct];
        }
    }

    // ---- conv-out (+b2) -> bf16 LDS tile Ht (C-layout scatter; LDS absorbs it) ----
#pragma unroll
    for (int ct = 0; ct < 2; ct++) {
        float bb = b2l[w * 32 + ct * 16 + i];
#pragma unroll
        for (int rt = 0; rt < 2; rt++)
#pragma unroll
            for (int r = 0; r < 4; r++)
                Ht[(rt * 16 + q * 4 + r) * HT_LD + w * 32 + ct * 16 + i] =
                    f2b(acc2[rt][ct][r] + bb);
    }
    __syncthreads();

    // ---- row-wise COALESCED epilogue: residual add, h store, LN(128), zb store ----
    {
        const unsigned int* Ht32 = (const unsigned int*)Ht;
        unsigned int* h32 = (unsigned int*)h;
        unsigned int* zb32 = (unsigned int*)zb;
        float2 gg = *(const float2*)&gn[lane * 2];
        float2 cc = *(const float2*)&bn[lane * 2];
        for (int rr = w; rr < BM; rr += 4) {
            int row = nb + rr;
            if (row >= NN) break;
            unsigned int tv = Ht32[rr * (HT_LD / 2) + lane];
            float cx = b2f((unsigned short)tv), cy = b2f((unsigned short)(tv >> 16));
            if (add_residual) {
                unsigned int hv = h32[(size_t)row * 64 + lane];
                cx += b2f((unsigned short)hv);
                cy += b2f((unsigned short)(hv >> 16));
            }
            h32[(size_t)row * 64 + lane] = pack2(cx, cy);
            float s = cx + cy, sq = cx * cx + cy * cy;
#pragma unroll
            for (int m = 32; m >= 1; m >>= 1) {
                s += __shfl_xor(s, m);
                sq += __shfl_xor(sq, m);
            }
            float mu = s * (1.f / 128.f);
            float var = sq * (1.f / 128.f) - mu * mu;
            float inv = rsqrtf(var + LNEPS);
            float z0 = fmaxf(fmaf((cx - mu) * inv, gg.x, cc.x), 0.f);
            float z1 = fmaxf(fmaf((cy - mu) * inv, gg.y, cc.y), 0.f);
            zb32[(size_t)row * 64 + lane] = pack2(z0, z1);
        }
    }
}

// ---------------- atomic-free global mean pool (batch is sorted) ----------------
__global__ void k_gbounds(const int* __restrict__ batch, int* __restrict__ gstart) {
    int g = blockIdx.x * blockDim.x + threadIdx.x;
    if (g > NG) return;
    int lo = 0, hi = NN;
    while (lo < hi) {
        int mid = (lo + hi) >> 1;
        if (batch[mid] < g) lo = mid + 1;
        else hi = mid;
    }
    gstart[g] = lo;
}

__global__ void k_pool(const unsigned short* __restrict__ zb, const int* __restrict__ gstart,
                       float* __restrict__ out) {
    int g = blockIdx.x;
    int c = threadIdx.x;  // 128
    int a = gstart[g], b = gstart[g + 1];
    float s0 = 0.f, s1 = 0.f;
    int n = a;
    for (; n + 2 <= b; n += 2) {
        s0 += b2f(zb[(size_t)n * HD + c]);
        s1 += b2f(zb[(size_t)(n + 1) * HD + c]);
    }
    if (n < b) s0 += b2f(zb[(size_t)n * HD + c]);
    out[g * HD + c] = (s0 + s1) / fmaxf((float)(b - a), 1.f);
}

// ---------------- launch ----------------
extern "C" void kernel_launch(void* const* d_in, const int* in_sizes, int n_in, void* d_out,
                              int out_size, void* d_ws, size_t ws_size, hipStream_t stream) {
    const float* x     = (const float*)d_in[0];
    const int* ei      = (const int*)d_in[1];
    const float* eattr = (const float*)d_in[2];
    const int* batch   = (const int*)d_in[3];
    const float* encW  = (const float*)d_in[4];
    const float* encB  = (const float*)d_in[5];
    const float* eW    = (const float*)d_in[6];
    const float* eB    = (const float*)d_in[7];
    const float* ln_g  = (const float*)d_in[8];
    const float* ln_b  = (const float*)d_in[9];
    const float* W1    = (const float*)d_in[10];
    const float* b1    = (const float*)d_in[11];
    const float* mlg   = (const float*)d_in[12];
    const float* mlb   = (const float*)d_in[13];
    const float* W2    = (const float*)d_in[14];
    const float* b2    = (const float*)d_in[15];
    const float* t     = (const float*)d_in[16];
    const int* src = ei;
    const int* dst = ei + NE;

    char* w = (char*)d_ws;
    auto alloc = [&](size_t bytes) {
        char* p = w;
        w += (bytes + 255) & ~size_t(255);
        return p;
    };
    unsigned short* h    = (unsigned short*)alloc(sizeof(unsigned short) * NN * HD);
    unsigned short* zb   = (unsigned short*)alloc(sizeof(unsigned short) * NN * HD);
    unsigned int* outb   = (unsigned int*)alloc(sizeof(unsigned int) * NN * HD / 2);
    float4* aperm        = (float4*)alloc(sizeof(float4) * NE);
    int* row_start       = (int*)alloc(sizeof(int) * (NN + 1));
    int* counts          = (int*)alloc(sizeof(int) * NN);
    int* cursor          = (int*)alloc(sizeof(int) * NN);
    int* incl            = (int*)alloc(sizeof(int) * NN);
    int* bsum            = (int*)alloc(sizeof(int) * 128);
    int* boff            = (int*)alloc(sizeof(int) * 128);
    int* gstart          = (int*)alloc(sizeof(int) * (NG + 1));
    unsigned short* W1T  = (unsigned short*)alloc(sizeof(unsigned short) * NL * HD * HD2);
    unsigned short* W2T  = (unsigned short*)alloc(sizeof(unsigned short) * NL * HD2 * HD);

    hipMemsetAsync(counts, 0, sizeof(int) * NN, stream);
    hipMemsetAsync(cursor, 0, sizeof(int) * NN, stream);

    k_prep<<<512, 256, 0, stream>>>(W1, W2, W1T, W2T);
    k_encode_nodes<<<NN, HD, 0, stream>>>(x, encW, encB, zb);
    k_hist<<<(NE + 255) / 256, 256, 0, stream>>>(dst, counts);
    int nsb = (NN + SCAN_B - 1) / SCAN_B;
    k_scan1<<<nsb, SCAN_B, 0, stream>>>(counts, incl, bsum);
    k_scan2<<<1, 128, 0, stream>>>(bsum, boff, nsb);
    k_scan3<<<nsb, SCAN_B, 0, stream>>>(incl, boff, row_start);
    k_scatter<<<(NE + 255) / 256, 256, 0, stream>>>(src, dst, eattr, row_start, cursor, aperm);
    k_gbounds<<<(NG + 256) / 256, 256, 0, stream>>>(batch, gstart);

    for (int l = 0; l < NL; l++) {
        k_aggregate<<<(NN + 3) / 4, 256, 0, stream>>>(zb, aperm, row_start, eW, eB, t, l, outb);
        int ln_next = (l + 1) % NL;  // layer 3 fuses the final ln (reuses layer-0 params)
        k_mlp<<<(NN + BM - 1) / BM, 256, 0, stream>>>(
            (const unsigned short*)outb, W1T + (size_t)l * HD * HD2, b1 + l * HD2,
            mlg + l * HD2, mlb + l * HD2, W2T + (size_t)l * HD2 * HD, b2 + l * HD, h,
            ln_g + ln_next * HD, ln_b + ln_next * HD, zb, l > 0);
    }
    k_pool<<<NG, HD, 0, stream>>>(zb, gstart, (float*)d_out);
}